// Round 8
// baseline (1205.046 us; speedup 1.0000x reference)
//
#include <hip/hip_runtime.h>
#include <hip/hip_bf16.h>

#define H 125
#define G4 500      // 4*H
#define NN 1024
#define DMLP 100

typedef __attribute__((ext_vector_type(4))) float f32x4;
typedef __attribute__((ext_vector_type(4))) int   i32x4;
typedef __attribute__((ext_vector_type(8))) int   i32x8;

__device__ __forceinline__ float frcp(float x) { return __builtin_amdgcn_rcpf(x); }

// f32 -> f32 rounded to bf16 precision (low 16 mantissa bits zero).
__device__ __forceinline__ float bf16_quant(float v) {
    return __bfloat162float(__float2bfloat16(v));
}

// ---------------------------------------------------------------- embedding
__global__ void embed_k(const int* __restrict__ wid, const int* __restrict__ pid,
                        const float* __restrict__ wemb, const float* __restrict__ pemb,
                        float* __restrict__ emb)
{
    int t = blockIdx.x;
    int i = threadIdx.x;
    if (i < 100)      emb[t * H + i] = wemb[wid[t] * 100 + i];
    else if (i < H)   emb[t * H + i] = pemb[pid[t] * 25 + (i - 100)];
}

// ---------------------------------------------- input GEMM: xg4 = x@Wih.T + b
// Output layout [t][u][4]: xg4[t*512 + u*4 + g] (g = i,f,g,o). Pads u>=125 zero.
template<int K>
__global__ __launch_bounds__(512) void ingemm4_k(
    const float* __restrict__ x,
    const float* __restrict__ wf, const float* __restrict__ bif, const float* __restrict__ bhf,
    const float* __restrict__ wb, const float* __restrict__ bib, const float* __restrict__ bhb,
    float* __restrict__ xg4f, float* __restrict__ xg4b)
{
    __shared__ float xs[8][K];
    const int dir = blockIdx.y;
    const float* __restrict__ w  = dir ? wb  : wf;
    const float* __restrict__ bi = dir ? bib : bif;
    const float* __restrict__ bh = dir ? bhb : bhf;
    float* __restrict__ xg       = dir ? xg4b : xg4f;

    const int t0  = blockIdx.x * 8;
    const int tid = threadIdx.x;
    for (int i = tid; i < 8 * K; i += 512) {
        int r = i / K;
        xs[r][i - r * K] = x[t0 * K + i];
    }
    __syncthreads();

    if (tid < G4) {
        const int g = tid / 125;
        const int u = tid - g * 125;
        const float* wr = w + tid * K;
        float base = bi[tid] + bh[tid];
        float acc[8];
#pragma unroll
        for (int tt = 0; tt < 8; ++tt) acc[tt] = base;
        for (int k = 0; k < K; ++k) {
            float wv = wr[k];
#pragma unroll
            for (int tt = 0; tt < 8; ++tt) acc[tt] += wv * xs[tt][k];
        }
#pragma unroll
        for (int tt = 0; tt < 8; ++tt) xg[(t0 + tt) * 512 + u * 4 + g] = acc[tt];
    } else {
        const int qq = tid - G4;   // pad slots 500..511
#pragma unroll
        for (int tt = 0; tt < 8; ++tt) xg[(t0 + tt) * 512 + G4 + qq] = 0.f;
    }
}

// --------------------------------- Whh -> fp8(e4m3) MFMA A-fragment prep
// Fragment for MX mfma 16x16x128: lane l holds rows R = tg*16 + (l&15),
// k = (l>>4)*32 + e, e=0..31 (32 bytes = 8 dwords). R = 4u+g interleaved.
__global__ __launch_bounds__(64) void whhprep8_k(
    const float* __restrict__ whh_f, const float* __restrict__ whh_b,
    int* __restrict__ out)
{
    const int dir = blockIdx.y;
    const float* __restrict__ whh = dir ? whh_b : whh_f;
    const int tg = blockIdx.x;        // 0..31
    const int l  = threadIdx.x;
    const int R  = tg * 16 + (l & 15);
    const int u  = R >> 2, g = R & 3;
    const int kb = (l >> 4) * 32;
    float f[32];
#pragma unroll
    for (int e = 0; e < 32; ++e) {
        const int k = kb + e;
        f[e] = (u < H && k < H) ? whh[(g * H + u) * H + k] : 0.f;
    }
    int* dst = out + ((dir * 32 + tg) * 64 + l) * 8;
#pragma unroll
    for (int j = 0; j < 8; ++j) {
        int lo = __builtin_amdgcn_cvt_pk_fp8_f32(f[4 * j + 0], f[4 * j + 1], 0,  false);
        int wv = __builtin_amdgcn_cvt_pk_fp8_f32(f[4 * j + 2], f[4 * j + 3], lo, true);
        dst[j] = wv;
    }
}

// ------------------------------------------------------------- LSTM scan v5
// grid = 2 (dir), block = 256 (4 waves, 1/SIMD, full VGPR budget).
// Wave w: row-tiles 8w..8w+7 (units 32w..32w+31), 8 MX MFMA/step.
// B = h fp8 col-replicated from LDS (2x ds_read_b128/lane). acc init = xg f32
// (4-step-deep register prefetch, loaded directly into consumed regs).
// D: lane(q,c) tile rt holds all 4 gates of unit 32w+4rt+q; c&7 selects rt.
__global__ __launch_bounds__(256, 1) void lstm_scan5_k(
    const float* __restrict__ xg_f, const float* __restrict__ xg_b,
    const int* __restrict__ whhA,
    float* __restrict__ hout)   // [NN][250]
{
    __shared__ __align__(16) unsigned char hb8[2][128];
    const int dir = blockIdx.x;
    const float* __restrict__ xg = dir ? xg_b : xg_f;
    const int col = dir ? H : 0;

    const int tid = threadIdx.x;
    const int w = tid >> 6;
    const int l = tid & 63;
    const int q = l >> 4;          // k-block group / D-row group
    const int c = l & 15;          // replicated column

    i32x8 A[8];
    const i32x8* Ab = (const i32x8*)whhA;
#pragma unroll
    for (int rt = 0; rt < 8; ++rt)
        A[rt] = Ab[(dir * 32 + w * 8 + rt) * 64 + l];

    if (tid < 128) { hb8[0][tid] = 0; hb8[1][tid] = 0; }
    __syncthreads();

    const int rsel = c & 7;
    const int usel = 32 * w + 4 * rsel + q;   // unit this lane activates
    const bool writer = (c < 8);
    const int xb = 128 * w + 4 * q;           // xg base; tile rt at +16*rt

    float cst = 0.f;
    int pp = 0;
    auto T = [&](int s) { return dir ? (NN - 1 - s) : s; };

    auto LOADALL = [&](int s_, f32x4 (&dst)[8]) {
        const int sc = (s_ < NN) ? s_ : NN - 1;
        const float* base = xg + T(sc) * 512 + xb;
#pragma unroll
        for (int rt = 0; rt < 8; ++rt)
            dst[rt] = *(const f32x4*)(base + 16 * rt);
    };

    auto STEP = [&](int t, const f32x4 (&x)[8]) {
        const unsigned char* hr = hb8[pp] + 32 * q;
        i32x4 blo = *(const i32x4*)hr;
        i32x4 bhi = *(const i32x4*)(hr + 16);
        i32x8 B;
        B[0] = blo[0]; B[1] = blo[1]; B[2] = blo[2]; B[3] = blo[3];
        B[4] = bhi[0]; B[5] = bhi[1]; B[6] = bhi[2]; B[7] = bhi[3];
        f32x4 a0 = __builtin_amdgcn_mfma_scale_f32_16x16x128_f8f6f4(
            A[0], B, x[0], 0, 0, 0, 0x7F7F7F7F, 0, 0x7F7F7F7F);
        f32x4 a1 = __builtin_amdgcn_mfma_scale_f32_16x16x128_f8f6f4(
            A[1], B, x[1], 0, 0, 0, 0x7F7F7F7F, 0, 0x7F7F7F7F);
        f32x4 a2 = __builtin_amdgcn_mfma_scale_f32_16x16x128_f8f6f4(
            A[2], B, x[2], 0, 0, 0, 0x7F7F7F7F, 0, 0x7F7F7F7F);
        f32x4 a3 = __builtin_amdgcn_mfma_scale_f32_16x16x128_f8f6f4(
            A[3], B, x[3], 0, 0, 0, 0x7F7F7F7F, 0, 0x7F7F7F7F);
        f32x4 a4 = __builtin_amdgcn_mfma_scale_f32_16x16x128_f8f6f4(
            A[4], B, x[4], 0, 0, 0, 0x7F7F7F7F, 0, 0x7F7F7F7F);
        f32x4 a5 = __builtin_amdgcn_mfma_scale_f32_16x16x128_f8f6f4(
            A[5], B, x[5], 0, 0, 0, 0x7F7F7F7F, 0, 0x7F7F7F7F);
        f32x4 a6 = __builtin_amdgcn_mfma_scale_f32_16x16x128_f8f6f4(
            A[6], B, x[6], 0, 0, 0, 0x7F7F7F7F, 0, 0x7F7F7F7F);
        f32x4 a7 = __builtin_amdgcn_mfma_scale_f32_16x16x128_f8f6f4(
            A[7], B, x[7], 0, 0, 0, 0x7F7F7F7F, 0, 0x7F7F7F7F);

        // 3-level select of acc[c&7]
        f32x4 s0 = (c & 1) ? a1 : a0;
        f32x4 s1 = (c & 1) ? a3 : a2;
        f32x4 s2 = (c & 1) ? a5 : a4;
        f32x4 s3 = (c & 1) ? a7 : a6;
        f32x4 u0 = (c & 2) ? s1 : s0;
        f32x4 u1 = (c & 2) ? s3 : s2;
        f32x4 gv = (c & 4) ? u1 : u0;

        const float gi = gv.x, gf = gv.y, gg = gv.z, go = gv.w;
        const float ai = frcp(1.f + __expf(-gi));
        const float af = frcp(1.f + __expf(-gf));
        const float ag = 2.f * frcp(1.f + __expf(-2.f * gg)) - 1.f;
        const float ao = frcp(1.f + __expf(-go));
        cst = af * cst + ai * ag;
        const float hv = ao * (2.f * frcp(1.f + __expf(-2.f * cst)) - 1.f);
        if (writer) {
            int pk = __builtin_amdgcn_cvt_pk_fp8_f32(hv, 0.f, 0, false);
            hb8[pp ^ 1][usel] = (unsigned char)(pk & 0xFF);
            if (usel < H) hout[t * 250 + col + usel] = hv;
        }
        asm volatile("s_waitcnt lgkmcnt(0)" ::: "memory");
        __builtin_amdgcn_s_barrier();
        __builtin_amdgcn_sched_barrier(0);
        pp ^= 1;
    };

    f32x4 P[8], Qr[8], N0[8], N1[8];
    LOADALL(0, P);
    LOADALL(1, Qr);
#pragma unroll 1
    for (int s = 0; s < NN; s += 4) {
        LOADALL(s + 2, N0);
        LOADALL(s + 3, N1);
        STEP(T(s),     P);
        STEP(T(s + 1), Qr);
        LOADALL(s + 4, P);
        LOADALL(s + 5, Qr);
        STEP(T(s + 2), N0);
        STEP(T(s + 3), N1);
    }
}

// --------------------------------------------- heads/mods: h1@w.T + b, 8 t/block
__global__ __launch_bounds__(256) void headmod_k(
    const float* __restrict__ h1,
    const float* __restrict__ w1, const float* __restrict__ b1,
    const float* __restrict__ w2, const float* __restrict__ b2,
    float* __restrict__ heads, float* __restrict__ mods)
{
    __shared__ float xs[8][250];
    const int t0  = blockIdx.x * 8;
    const int tid = threadIdx.x;
    for (int i = tid; i < 8 * 250; i += 256) {
        int r = i / 250;
        xs[r][i - r * 250] = h1[t0 * 250 + i];
    }
    __syncthreads();

    int d; const float* w; float bb; float* o;
    if (tid < DMLP)                          { d = tid;       w = w1 + d * 250; bb = b1[d]; o = heads; }
    else if (tid >= 128 && tid < 128 + DMLP) { d = tid - 128; w = w2 + d * 250; bb = b2[d]; o = mods;  }
    else return;

    float acc[8];
#pragma unroll
    for (int tt = 0; tt < 8; ++tt) acc[tt] = bb;
    for (int k = 0; k < 250; ++k) {
        float wv = w[k];
#pragma unroll
        for (int tt = 0; tt < 8; ++tt) acc[tt] += wv * xs[tt][k];
    }
#pragma unroll
    for (int tt = 0; tt < 8; ++tt) o[(t0 + tt) * DMLP + d] = acc[tt];
}

// ----------------------------------------------------------------- scores
__global__ __launch_bounds__(256) void scores_k(
    const float* __restrict__ heads, const float* __restrict__ mods,
    const float* __restrict__ w3, const float* __restrict__ b3,
    float* __restrict__ out)
{
    __shared__ __align__(16) float hh[16][DMLP];
    __shared__ __align__(16) float mm[16][DMLP];
    __shared__ __align__(16) float ws3[DMLP];
    const int bh = blockIdx.y * 16, bm = blockIdx.x * 16;
    const int tid = threadIdx.x;
    for (int i = tid; i < 16 * DMLP; i += 256) {
        int r = i / DMLP, d = i - r * DMLP;
        hh[r][d] = heads[(bh + r) * DMLP + d];
        mm[r][d] = mods[(bm + r) * DMLP + d];
    }
    if (tid < DMLP) ws3[tid] = w3[tid];
    __syncthreads();

    const int tx = tid & 15, ty = tid >> 4;
    const f32x4* h4 = (const f32x4*)hh[ty];
    const f32x4* m4 = (const f32x4*)mm[tx];
    const f32x4* w4 = (const f32x4*)ws3;
    float acc = 0.f;
#pragma unroll
    for (int qq = 0; qq < DMLP / 4; ++qq) {
        f32x4 v  = h4[qq] + m4[qq];
        f32x4 wv = w4[qq];
#pragma unroll
        for (int e = 0; e < 4; ++e) {
            float th = 2.f * frcp(1.f + __expf(-2.f * v[e])) - 1.f;
            acc += wv[e] * th;
        }
    }
    acc += b3[0];
    const int hrow = bh + ty, mcol = bm + tx;
    float v = (hrow == mcol) ? -3.3895313892515355e38f : bf16_quant(acc);
    out[hrow * NN + mcol] = v;
}

// ----------------------------------------------------------------- launch
extern "C" void kernel_launch(void* const* d_in, const int* in_sizes, int n_in,
                              void* d_out, int out_size, void* d_ws, size_t ws_size,
                              hipStream_t stream)
{
    const int*   wid   = (const int*)d_in[0];
    const int*   pid   = (const int*)d_in[1];
    const float* wemb  = (const float*)d_in[3];
    const float* pemb  = (const float*)d_in[4];
    const float* wih0f = (const float*)d_in[5];
    const float* whh0f = (const float*)d_in[6];
    const float* bih0f = (const float*)d_in[7];
    const float* bhh0f = (const float*)d_in[8];
    const float* wih0b = (const float*)d_in[9];
    const float* whh0b = (const float*)d_in[10];
    const float* bih0b = (const float*)d_in[11];
    const float* bhh0b = (const float*)d_in[12];
    const float* wih1f = (const float*)d_in[13];
    const float* whh1f = (const float*)d_in[14];
    const float* bih1f = (const float*)d_in[15];
    const float* bhh1f = (const float*)d_in[16];
    const float* wih1b = (const float*)d_in[17];
    const float* whh1b = (const float*)d_in[18];
    const float* bih1b = (const float*)d_in[19];
    const float* bhh1b = (const float*)d_in[20];
    const float* w1    = (const float*)d_in[21];
    const float* b1    = (const float*)d_in[22];
    const float* w2    = (const float*)d_in[23];
    const float* b2    = (const float*)d_in[24];
    const float* w3    = (const float*)d_in[25];
    const float* b3    = (const float*)d_in[26];

    float* ws    = (float*)d_ws;
    float* emb   = ws;                  // 128000
    float* xgf   = ws + 128000;         // 524288
    float* xgb   = ws + 652288;         // 524288
    float* h0    = ws + 1176576;        // 256000
    float* h1    = ws + 1432576;        // 256000
    float* hd    = ws + 1688576;        // 102400
    float* md    = ws + 1790976;        // 102400
    int*   whhA0 = (int*)(ws + 1893376);  // 2*32*64*8 i32 = 32768 (128 KB)
    int*   whhA1 = (int*)(ws + 1926144);  // 32768

    embed_k<<<NN, 128, 0, stream>>>(wid, pid, wemb, pemb, emb);
    whhprep8_k<<<dim3(32, 2), 64, 0, stream>>>(whh0f, whh0b, whhA0);
    whhprep8_k<<<dim3(32, 2), 64, 0, stream>>>(whh1f, whh1b, whhA1);

    ingemm4_k<125><<<dim3(NN / 8, 2), 512, 0, stream>>>(
        emb, wih0f, bih0f, bhh0f, wih0b, bih0b, bhh0b, xgf, xgb);

    lstm_scan5_k<<<2, 256, 0, stream>>>(xgf, xgb, whhA0, h0);

    ingemm4_k<250><<<dim3(NN / 8, 2), 512, 0, stream>>>(
        h0, wih1f, bih1f, bhh1f, wih1b, bih1b, bhh1b, xgf, xgb);

    lstm_scan5_k<<<2, 256, 0, stream>>>(xgf, xgb, whhA1, h1);

    headmod_k<<<NN / 8, 256, 0, stream>>>(h1, w1, b1, w2, b2, hd, md);

    scores_k<<<dim3(NN / 16, NN / 16), 256, 0, stream>>>(hd, md, w3, b3, (float*)d_out);
}